// Round 1
// baseline (220.221 us; speedup 1.0000x reference)
//
#include <hip/hip_runtime.h>
#include <float.h>
#include <math.h>

// Problem constants: B=16, L=1024, D=512, DH=64, H=8, ktop=13
#define PROJ_N (16*64*1024)   // 1048576 floats per projected tensor (layout [b*64+d][l])

// ---------------------------------------------------------------------------
// Kernel A: q/k/v = X @ Wq + bq for X in {Q,K,V}, stored TRANSPOSED:
//   proj[in][(b*64+d)*1024 + l]
// grid = 768 (3 inputs * 256 row-tiles of 64), block = 256
// 64l x 64d tile, K-chunks of 64, per-thread 4l x 4d micro-tile.
// X staged transposed into LDS with XOR-chunk swizzle (writes & reads <=2-way).
// ---------------------------------------------------------------------------
__global__ __launch_bounds__(256) void proj_kernel(
    const float* __restrict__ Q, const float* __restrict__ K,
    const float* __restrict__ V, const float* __restrict__ Wq,
    const float* __restrict__ bq, float* __restrict__ proj) {
  __shared__ float XsT[64 * 64];  // logical (k,l); phys chunk = (l>>2) ^ ((k>>2)&7)
  __shared__ float Ws[64 * 64];   // (k,d) row-major

  const int blk  = blockIdx.x;
  const int in   = blk >> 8;            // 0..2
  const int row0 = (blk & 255) << 6;    // global row (b*1024 + l), 64-row tile
  const float* __restrict__ X = (in == 0) ? Q : (in == 1 ? K : V);

  const int t  = threadIdx.x;
  const int c4 = t & 15;   // k-quad during staging
  const int rr = t >> 4;   // row group during staging
  const int tx = t & 15;   // d-quad during compute
  const int ty = t >> 4;   // l-quad during compute

  float acc[4][4] = {{0.f,0.f,0.f,0.f},{0.f,0.f,0.f,0.f},
                     {0.f,0.f,0.f,0.f},{0.f,0.f,0.f,0.f}};

  for (int kt = 0; kt < 8; ++kt) {
    const int k0 = kt << 6;
    __syncthreads();   // protect LDS reuse (harmless on first iter)

    // ---- stage X (transposed + swizzled) and W ----
#pragma unroll
    for (int it = 0; it < 4; ++it) {
      const int r = it * 16 + rr;   // 0..63 (l within tile / k-row for W)
      float4 f = *(const float4*)&X[(size_t)(row0 + r) * 512 + k0 + 4 * c4];
      const int sw = ((((r >> 2) ^ (c4 & 7)) << 2) | (r & 3));
      XsT[(4 * c4 + 0) * 64 + sw] = f.x;
      XsT[(4 * c4 + 1) * 64 + sw] = f.y;
      XsT[(4 * c4 + 2) * 64 + sw] = f.z;
      XsT[(4 * c4 + 3) * 64 + sw] = f.w;
      float4 g = *(const float4*)&Wq[(size_t)(k0 + r) * 64 + 4 * c4];
      *(float4*)&Ws[r * 64 + 4 * c4] = g;
    }
    __syncthreads();

    // ---- compute ----
#pragma unroll 4
    for (int kk = 0; kk < 64; ++kk) {
      const int sk = (kk >> 2) & 7;
      float4 x4 = *(float4*)&XsT[kk * 64 + ((ty ^ sk) << 2)];
      float4 wv = *(float4*)&Ws[kk * 64 + 4 * tx];
      acc[0][0] += x4.x * wv.x; acc[0][1] += x4.x * wv.y;
      acc[0][2] += x4.x * wv.z; acc[0][3] += x4.x * wv.w;
      acc[1][0] += x4.y * wv.x; acc[1][1] += x4.y * wv.y;
      acc[1][2] += x4.y * wv.z; acc[1][3] += x4.y * wv.w;
      acc[2][0] += x4.z * wv.x; acc[2][1] += x4.z * wv.y;
      acc[2][2] += x4.z * wv.z; acc[2][3] += x4.z * wv.w;
      acc[3][0] += x4.w * wv.x; acc[3][1] += x4.w * wv.y;
      acc[3][2] += x4.w * wv.z; acc[3][3] += x4.w * wv.w;
    }
  }

  // ---- epilogue: add bias, store transposed ----
  const int b  = row0 >> 10;
  const int l0 = row0 & 1023;
  float* __restrict__ op = proj + (size_t)in * PROJ_N + (size_t)(b * 64) * 1024;
#pragma unroll
  for (int j = 0; j < 4; ++j) {
    const int d = 4 * tx + j;
    const float bias = bq[d];
    float4 o = make_float4(acc[0][j] + bias, acc[1][j] + bias,
                           acc[2][j] + bias, acc[3][j] + bias);
    *(float4*)&op[(size_t)d * 1024 + l0 + 4 * ty] = o;
  }
}

// ---------------------------------------------------------------------------
// Kernel B: circular correlation corr[s] = sum_l q[l]*k[(l-s) mod 1024],
// top-13 + softmax.  grid = 1024 (one block per (b,d) pair), block = 128.
// Per-thread s = 8t..8t+7, sliding 11-word register window over k_ext
// (k duplicated to 2048, stored parity-split so refills are conflict-free).
// ---------------------------------------------------------------------------
__global__ __launch_bounds__(128) void corr_topk_kernel(
    const float* __restrict__ qp, const float* __restrict__ kp,
    float* __restrict__ wvals, int* __restrict__ widx) {
  __shared__ float qs[1024];
  __shared__ float ks8[2048];   // word = ((p<<1)|e)*256 + c2 ; element 4c+p, e=c&1, c2=c>>1
  __shared__ float tv[13];
  __shared__ int   ts[13];
  __shared__ float rwv[2];
  __shared__ int   rws[2];
  __shared__ int   bsh;

  const int pair = blockIdx.x;
  const int t = threadIdx.x;
  const float* __restrict__ qg = qp + (size_t)pair * 1024;
  const float* __restrict__ kg = kp + (size_t)pair * 1024;

  // load q (1024 floats)
  *(float4*)&qs[4 * t]         = *(const float4*)&qg[4 * t];
  *(float4*)&qs[4 * (t + 128)] = *(const float4*)&qg[4 * (t + 128)];
  // load k_ext (2048 elements) into parity-split layout
#pragma unroll
  for (int jj = 0; jj < 4; ++jj) {
    const int j = t + jj * 128;               // chunk index c = j, 0..511
    float4 f = *(const float4*)&kg[(4 * j) & 1023];
    const int e = j & 1, c2 = j >> 1;
    ks8[(0 * 2 + e) * 256 + c2] = f.x;
    ks8[(1 * 2 + e) * 256 + c2] = f.y;
    ks8[(2 * 2 + e) * 256 + c2] = f.z;
    ks8[(3 * 2 + e) * 256 + c2] = f.w;
  }
  __syncthreads();

  // init window: w[m] = k_ext[Bt + m], Bt = 1017 - 8t  (g in [1,1027])
  float w[11];
  const int Bt = 1017 - 8 * t;
#pragma unroll
  for (int m = 0; m < 11; ++m) {
    const int g = Bt + m;
    w[m] = ks8[(((g & 3) << 1) | ((g >> 2) & 1)) * 256 + (g >> 3)];
  }

  float acc[8] = {0.f,0.f,0.f,0.f,0.f,0.f,0.f,0.f};
  // acc[i] (s = 8t+i) += q[4lc+j] * w[j - i + 7]
#pragma unroll 4
  for (int lc = 0; lc < 255; ++lc) {
    float4 q4 = *(float4*)&qs[4 * lc];
#pragma unroll
    for (int i = 0; i < 8; ++i)
      acc[i] += q4.x * w[7 - i] + q4.y * w[8 - i] + q4.z * w[9 - i] + q4.w * w[10 - i];
    // slide window by 4 and refill w[7..10] (elements 4c..4c+3, c = lc+257-2t)
#pragma unroll
    for (int m = 0; m < 7; ++m) w[m] = w[m + 4];
    const int c = lc + 257 - 2 * t;
    const int base = ((c & 1) << 8) + (c >> 1);
    w[7]  = ks8[base];
    w[8]  = ks8[512 + base];
    w[9]  = ks8[1024 + base];
    w[10] = ks8[1536 + base];
  }
  {   // last chunk (no refill)
    float4 q4 = *(float4*)&qs[4 * 255];
#pragma unroll
    for (int i = 0; i < 8; ++i)
      acc[i] += q4.x * w[7 - i] + q4.y * w[8 - i] + q4.z * w[9 - i] + q4.w * w[10 - i];
  }

  // ---- top-13 via iterative argmax ----
  for (int r = 0; r < 13; ++r) {
    float m = acc[0]; int mi = 0;
#pragma unroll
    for (int i = 1; i < 8; ++i)
      if (acc[i] > m) { m = acc[i]; mi = i; }
    int ms = 8 * t + mi;
#pragma unroll
    for (int off = 32; off >= 1; off >>= 1) {
      float om = __shfl_xor(m, off, 64);
      int   os = __shfl_xor(ms, off, 64);
      if (om > m || (om == m && os < ms)) { m = om; ms = os; }
    }
    if ((t & 63) == 0) { rwv[t >> 6] = m; rws[t >> 6] = ms; }
    __syncthreads();
    if (t == 0) {
      float bv = rwv[0]; int bs = rws[0];
      if (rwv[1] > bv || (rwv[1] == bv && rws[1] < bs)) { bv = rwv[1]; bs = rws[1]; }
      tv[r] = bv; ts[r] = bs; bsh = bs;
    }
    __syncthreads();
    const int bs = bsh;
    if ((bs >> 3) == t) acc[bs & 7] = -FLT_MAX;
  }

  // ---- softmax over the 13 values (thread 0) ----
  if (t == 0) {
    const float mx = tv[0];
    float e[13]; float s = 0.f;
#pragma unroll
    for (int k = 0; k < 13; ++k) { e[k] = __expf(tv[k] - mx); s += e[k]; }
    const float inv = 1.f / s;
#pragma unroll
    for (int k = 0; k < 13; ++k) {
      wvals[pair * 16 + k] = e[k] * inv;
      widx [pair * 16 + k] = ts[k];
    }
  }
}

// ---------------------------------------------------------------------------
// Kernel C: agg[pair][l] = sum_k w_k * v[(l + idx_k) mod 1024]
// grid = 1024, block = 256
// ---------------------------------------------------------------------------
__global__ __launch_bounds__(256) void agg_kernel(
    const float* __restrict__ vp, const float* __restrict__ wvals,
    const int* __restrict__ widx, float* __restrict__ agg) {
  __shared__ float vs[2048];
  __shared__ float wv[13];
  __shared__ int   wi[13];
  const int pair = blockIdx.x;
  const int t = threadIdx.x;
  const float* __restrict__ vg = vp + (size_t)pair * 1024;
  *(float4*)&vs[4 * t]         = *(const float4*)&vg[(4 * t) & 1023];
  *(float4*)&vs[4 * (t + 256)] = *(const float4*)&vg[(4 * (t + 256)) & 1023];
  if (t < 13) { wv[t] = wvals[pair * 16 + t]; wi[t] = widx[pair * 16 + t]; }
  __syncthreads();

  float r0 = 0.f, r1 = 0.f, r2 = 0.f, r3 = 0.f;
#pragma unroll
  for (int k = 0; k < 13; ++k) {
    const float wk = wv[k];
    const int   ik = wi[k];
    r0 += wk * vs[t        + ik];
    r1 += wk * vs[t + 256  + ik];
    r2 += wk * vs[t + 512  + ik];
    r3 += wk * vs[t + 768  + ik];
  }
  float* __restrict__ ag = agg + (size_t)pair * 1024;
  ag[t] = r0; ag[t + 256] = r1; ag[t + 512] = r2; ag[t + 768] = r3;
}

// ---------------------------------------------------------------------------
// Kernel D: out[b][l][h*64+d] = agg[b*64+d][l]  (transpose + 8x head copy)
// grid = 256 (16 b * 16 l-tiles of 64), block = 256
// ---------------------------------------------------------------------------
__global__ __launch_bounds__(256) void out_kernel(
    const float* __restrict__ agg, float* __restrict__ out) {
  __shared__ float tile[64][65];
  const int blk = blockIdx.x;
  const int b = blk >> 4, lt = blk & 15;
  const int l0 = lt * 64;
  const int t = threadIdx.x;
  const int j = t & 63, qq = t >> 6;   // qq in 0..3

#pragma unroll
  for (int p = 0; p < 16; ++p) {
    const int d = p * 4 + qq;
    tile[d][j] = agg[(size_t)(b * 64 + d) * 1024 + l0 + j];
  }
  __syncthreads();
#pragma unroll
  for (int p = 0; p < 16; ++p) {
    const int jj = p * 4 + qq;                 // l offset within tile
    const float val = tile[j][jj];             // j acts as d here
    const size_t rowbase = ((size_t)(b * 1024 + l0 + jj)) * 512;
#pragma unroll
    for (int h = 0; h < 8; ++h)
      out[rowbase + h * 64 + j] = val;
  }
}

// ---------------------------------------------------------------------------
extern "C" void kernel_launch(void* const* d_in, const int* in_sizes, int n_in,
                              void* d_out, int out_size, void* d_ws, size_t ws_size,
                              hipStream_t stream) {
  const float* Q  = (const float*)d_in[0];
  const float* K  = (const float*)d_in[1];
  const float* V  = (const float*)d_in[2];
  const float* Wq = (const float*)d_in[3];
  const float* bq = (const float*)d_in[4];
  float* out = (float*)d_out;
  float* ws  = (float*)d_ws;

  float* proj  = ws;                              // 3 * 1048576 floats
  float* agg   = ws + (size_t)3 * PROJ_N;         // 1048576 floats
  float* wvals = ws + (size_t)4 * PROJ_N;         // 1024*16 floats
  int*   widx  = (int*)(ws + (size_t)4 * PROJ_N + 16384);  // 1024*16 ints

  proj_kernel<<<768, 256, 0, stream>>>(Q, K, V, Wq, bq, proj);
  corr_topk_kernel<<<1024, 128, 0, stream>>>(proj, proj + PROJ_N, wvals, widx);
  agg_kernel<<<1024, 256, 0, stream>>>(proj + (size_t)2 * PROJ_N, wvals, widx, agg);
  out_kernel<<<256, 256, 0, stream>>>(agg, out);
}

// Round 4
// 188.714 us; speedup vs baseline: 1.1670x; 1.1670x over previous
//
#include <hip/hip_runtime.h>
#include <float.h>
#include <math.h>

// Problem constants: B=16, L=1024, D=512, DH=64, H=8, ktop=13
#define PROJ_N (16*64*1024)   // 1048576 floats per projected tensor (layout [b*64+d][l])

using short8_t  = __attribute__((ext_vector_type(8)))  short;
using uint4_t   = __attribute__((ext_vector_type(4)))  unsigned;
using floatx16  = __attribute__((ext_vector_type(16))) float;

// ---------------------------------------------------------------------------
// Kernel A: q/k/v = X @ Wq + bq for X in {Q,K,V}, stored TRANSPOSED:
//   proj[in][(b*64+d)*1024 + l]   (unchanged)
// ---------------------------------------------------------------------------
__global__ __launch_bounds__(256) void proj_kernel(
    const float* __restrict__ Q, const float* __restrict__ K,
    const float* __restrict__ V, const float* __restrict__ Wq,
    const float* __restrict__ bq, float* __restrict__ proj) {
  __shared__ float XsT[64 * 64];  // logical (k,l); phys chunk = (l>>2) ^ ((k>>2)&7)
  __shared__ float Ws[64 * 64];   // (k,d) row-major

  const int blk  = blockIdx.x;
  const int in   = blk >> 8;            // 0..2
  const int row0 = (blk & 255) << 6;    // global row (b*1024 + l), 64-row tile
  const float* __restrict__ X = (in == 0) ? Q : (in == 1 ? K : V);

  const int t  = threadIdx.x;
  const int c4 = t & 15;
  const int rr = t >> 4;
  const int tx = t & 15;
  const int ty = t >> 4;

  float acc[4][4] = {{0.f,0.f,0.f,0.f},{0.f,0.f,0.f,0.f},
                     {0.f,0.f,0.f,0.f},{0.f,0.f,0.f,0.f}};

  for (int kt = 0; kt < 8; ++kt) {
    const int k0 = kt << 6;
    __syncthreads();
#pragma unroll
    for (int it = 0; it < 4; ++it) {
      const int r = it * 16 + rr;
      float4 f = *(const float4*)&X[(size_t)(row0 + r) * 512 + k0 + 4 * c4];
      const int sw = ((((r >> 2) ^ (c4 & 7)) << 2) | (r & 3));
      XsT[(4 * c4 + 0) * 64 + sw] = f.x;
      XsT[(4 * c4 + 1) * 64 + sw] = f.y;
      XsT[(4 * c4 + 2) * 64 + sw] = f.z;
      XsT[(4 * c4 + 3) * 64 + sw] = f.w;
      float4 g = *(const float4*)&Wq[(size_t)(k0 + r) * 64 + 4 * c4];
      *(float4*)&Ws[r * 64 + 4 * c4] = g;
    }
    __syncthreads();

#pragma unroll 4
    for (int kk = 0; kk < 64; ++kk) {
      const int sk = (kk >> 2) & 7;
      float4 x4 = *(float4*)&XsT[kk * 64 + ((ty ^ sk) << 2)];
      float4 wv = *(float4*)&Ws[kk * 64 + 4 * tx];
      acc[0][0] += x4.x * wv.x; acc[0][1] += x4.x * wv.y;
      acc[0][2] += x4.x * wv.z; acc[0][3] += x4.x * wv.w;
      acc[1][0] += x4.y * wv.x; acc[1][1] += x4.y * wv.y;
      acc[1][2] += x4.y * wv.z; acc[1][3] += x4.y * wv.w;
      acc[2][0] += x4.z * wv.x; acc[2][1] += x4.z * wv.y;
      acc[2][2] += x4.z * wv.z; acc[2][3] += x4.z * wv.w;
      acc[3][0] += x4.w * wv.x; acc[3][1] += x4.w * wv.y;
      acc[3][2] += x4.w * wv.z; acc[3][3] += x4.w * wv.w;
    }
  }

  const int b  = row0 >> 10;
  const int l0 = row0 & 1023;
  float* __restrict__ op = proj + (size_t)in * PROJ_N + (size_t)(b * 64) * 1024;
#pragma unroll
  for (int j = 0; j < 4; ++j) {
    const int d = 4 * tx + j;
    const float bias = bq[d];
    float4 o = make_float4(acc[0][j] + bias, acc[1][j] + bias,
                           acc[2][j] + bias, acc[3][j] + bias);
    *(float4*)&op[(size_t)d * 1024 + l0 + 4 * ty] = o;
  }
}

// ---------------------------------------------------------------------------
// bf16 helpers: RNE round, and hi/lo split (x = hi + lo, each bf16-exact)
// ---------------------------------------------------------------------------
__device__ __forceinline__ unsigned bf16r(float x) {
  unsigned u = __float_as_uint(x);
  return (u + 0x7FFFu + ((u >> 16) & 1u)) >> 16;
}
__device__ __forceinline__ unsigned pk_bf16(float x, float y) {
  return bf16r(x) | (bf16r(y) << 16);
}

// ---------------------------------------------------------------------------
// Kernel B: circular correlation via SPLIT-PRECISION bf16 MFMA (3 products:
// hi*hi + hi*lo + lo*hi), top-13 + softmax.
// One block per (b,d) pair; 4 waves split K=1024 (256 each, 16 steps).
//   C[row,col] = sum_kk  k[(kk - 32*row) mod L] * q[(kk + col) mod L]
//              = corr[col + 32*row],  all 1024 lags in one 32x32 tile.
// A-side (k): 16B-aligned ds_read_b128 from XOR-swizzled lines (hi & lo).
// B-side (q): 5 dword reads + v_alignbit per component (element shift).
// ---------------------------------------------------------------------------
__global__ __launch_bounds__(256) void corr_mfma_kernel(
    const float* __restrict__ qp, const float* __restrict__ kp,
    float* __restrict__ wvals, int* __restrict__ widx) {
  __shared__ __align__(16) short qh[2048];   // q_ext hi, linear lines
  __shared__ __align__(16) short ql[2048];   // q_ext lo, linear lines
  __shared__ __align__(16) short kh[2048];   // k_ext hi, line c at phys c^((c>>3)&7)
  __shared__ __align__(16) short kl[2048];   // k_ext lo, swizzled
  __shared__ float corr4[4][1024];
  __shared__ float tv[13];
  __shared__ int   ts[13];
  __shared__ float rv[4];
  __shared__ int   rs[4];
  __shared__ int   bsh;

  const int pair = blockIdx.x;
  const int tid  = threadIdx.x;
  const int w    = tid >> 6;
  const int lane = tid & 63;
  const int row  = lane & 31;
  const int hk   = lane >> 5;

  const float* __restrict__ qg = qp + (size_t)pair * 1024;
  const float* __restrict__ kg = kp + (size_t)pair * 1024;

  // ---- stage q_ext and k_ext as hi/lo bf16 pairs ----
  {
    const int j = (tid << 3) & 1023;          // both exts are periodic copies
    float4 a0 = *(const float4*)&qg[j];
    float4 a1 = *(const float4*)&qg[j + 4];
    float fq[8] = {a0.x, a0.y, a0.z, a0.w, a1.x, a1.y, a1.z, a1.w};
    unsigned hb[8]; float lf[8];
#pragma unroll
    for (int m = 0; m < 8; ++m) {
      hb[m] = bf16r(fq[m]);
      lf[m] = fq[m] - __uint_as_float(hb[m] << 16);
    }
    uint4_t vqh = { hb[0] | (hb[1] << 16), hb[2] | (hb[3] << 16),
                    hb[4] | (hb[5] << 16), hb[6] | (hb[7] << 16) };
    uint4_t vql = { pk_bf16(lf[0], lf[1]), pk_bf16(lf[2], lf[3]),
                    pk_bf16(lf[4], lf[5]), pk_bf16(lf[6], lf[7]) };
    *(uint4_t*)&qh[tid << 3] = vqh;
    *(uint4_t*)&ql[tid << 3] = vql;

    float4 b0 = *(const float4*)&kg[j];
    float4 b1 = *(const float4*)&kg[j + 4];
    float fk[8] = {b0.x, b0.y, b0.z, b0.w, b1.x, b1.y, b1.z, b1.w};
#pragma unroll
    for (int m = 0; m < 8; ++m) {
      hb[m] = bf16r(fk[m]);
      lf[m] = fk[m] - __uint_as_float(hb[m] << 16);
    }
    uint4_t vkh = { hb[0] | (hb[1] << 16), hb[2] | (hb[3] << 16),
                    hb[4] | (hb[5] << 16), hb[6] | (hb[7] << 16) };
    uint4_t vkl = { pk_bf16(lf[0], lf[1]), pk_bf16(lf[2], lf[3]),
                    pk_bf16(lf[4], lf[5]), pk_bf16(lf[6], lf[7]) };
    const int p = tid ^ ((tid >> 3) & 7);
    *(uint4_t*)&kh[p << 3] = vkh;
    *(uint4_t*)&kl[p << 3] = vkl;
  }
  __syncthreads();

  // ---- MFMA over this wave's K-chunk (3 products per step) ----
  floatx16 acc = {0.f,0.f,0.f,0.f,0.f,0.f,0.f,0.f,
                  0.f,0.f,0.f,0.f,0.f,0.f,0.f,0.f};
  const unsigned* __restrict__ qhd = (const unsigned*)qh;
  const unsigned* __restrict__ qld = (const unsigned*)ql;
#pragma unroll
  for (int i = 0; i < 16; ++i) {
    const int k0 = (w << 8) + (i << 4);
    // A fragments: k_ext[1024 + k0 + 8*hk - 32*row .. +7]
    const int e0 = 1024 + k0 + (hk << 3) - (row << 5);
    const int c  = e0 >> 3;
    const int p  = c ^ ((c >> 3) & 7);
    short8_t ah = *(const short8_t*)&kh[p << 3];
    short8_t al = *(const short8_t*)&kl[p << 3];
    // B fragments: q_ext[k0 + 8*hk + row .. +7]  (element-misaligned)
    const int s0 = k0 + (hk << 3) + row;
    const int d0 = s0 >> 1;
    const unsigned sh = (s0 & 1) << 4;
    unsigned w0 = qhd[d0 + 0], w1 = qhd[d0 + 1], w2 = qhd[d0 + 2],
             w3 = qhd[d0 + 3], w4 = qhd[d0 + 4];
    uint4_t buh = { __builtin_amdgcn_alignbit(w1, w0, sh),
                    __builtin_amdgcn_alignbit(w2, w1, sh),
                    __builtin_amdgcn_alignbit(w3, w2, sh),
                    __builtin_amdgcn_alignbit(w4, w3, sh) };
    unsigned x0 = qld[d0 + 0], x1 = qld[d0 + 1], x2 = qld[d0 + 2],
             x3 = qld[d0 + 3], x4 = qld[d0 + 4];
    uint4_t bul = { __builtin_amdgcn_alignbit(x1, x0, sh),
                    __builtin_amdgcn_alignbit(x2, x1, sh),
                    __builtin_amdgcn_alignbit(x3, x2, sh),
                    __builtin_amdgcn_alignbit(x4, x3, sh) };
    short8_t bh = __builtin_bit_cast(short8_t, buh);
    short8_t bl = __builtin_bit_cast(short8_t, bul);
    acc = __builtin_amdgcn_mfma_f32_32x32x16_bf16(ah, bh, acc, 0, 0, 0);
    acc = __builtin_amdgcn_mfma_f32_32x32x16_bf16(ah, bl, acc, 0, 0, 0);
    acc = __builtin_amdgcn_mfma_f32_32x32x16_bf16(al, bh, acc, 0, 0, 0);
  }

  // ---- write partials; C/D layout: col=lane&31, row=(r&3)+8*(r>>2)+4*hk ----
#pragma unroll
  for (int r = 0; r < 16; ++r) {
    const int srow = (r & 3) + ((r >> 2) << 3) + (hk << 2);
    corr4[w][(srow << 5) | row] = acc[r];
  }
  __syncthreads();

  // ---- reduce 4 partials; each thread owns s = {tid, tid+256, tid+512, tid+768}
  float v0 = corr4[0][tid]       + corr4[1][tid]       + corr4[2][tid]       + corr4[3][tid];
  float v1 = corr4[0][tid + 256] + corr4[1][tid + 256] + corr4[2][tid + 256] + corr4[3][tid + 256];
  float v2 = corr4[0][tid + 512] + corr4[1][tid + 512] + corr4[2][tid + 512] + corr4[3][tid + 512];
  float v3 = corr4[0][tid + 768] + corr4[1][tid + 768] + corr4[2][tid + 768] + corr4[3][tid + 768];

  // ---- top-13 via iterative block argmax ----
  for (int r = 0; r < 13; ++r) {
    float bv = v0; int bs = tid;
    if (v1 > bv) { bv = v1; bs = tid + 256; }
    if (v2 > bv) { bv = v2; bs = tid + 512; }
    if (v3 > bv) { bv = v3; bs = tid + 768; }
#pragma unroll
    for (int off = 32; off >= 1; off >>= 1) {
      float ov = __shfl_xor(bv, off, 64);
      int   os = __shfl_xor(bs, off, 64);
      if (ov > bv || (ov == bv && os < bs)) { bv = ov; bs = os; }
    }
    if (lane == 0) { rv[w] = bv; rs[w] = bs; }
    __syncthreads();
    if (tid == 0) {
      float cv = rv[0]; int cs = rs[0];
#pragma unroll
      for (int u = 1; u < 4; ++u)
        if (rv[u] > cv || (rv[u] == cv && rs[u] < cs)) { cv = rv[u]; cs = rs[u]; }
      tv[r] = cv; ts[r] = cs; bsh = cs;
    }
    __syncthreads();
    const int bw = bsh;
    if ((bw & 255) == tid) {
      const int slot = bw >> 8;
      if      (slot == 0) v0 = -FLT_MAX;
      else if (slot == 1) v1 = -FLT_MAX;
      else if (slot == 2) v2 = -FLT_MAX;
      else                v3 = -FLT_MAX;
    }
  }

  // ---- softmax over the 13 values (thread 0) ----
  if (tid == 0) {
    const float mx = tv[0];
    float e[13]; float s = 0.f;
#pragma unroll
    for (int k = 0; k < 13; ++k) { e[k] = __expf(tv[k] - mx); s += e[k]; }
    const float inv = 1.f / s;
#pragma unroll
    for (int k = 0; k < 13; ++k) {
      wvals[pair * 16 + k] = e[k] * inv;
      widx [pair * 16 + k] = ts[k];
    }
  }
}

// ---------------------------------------------------------------------------
// Kernel C: agg[pair][l] = sum_k w_k * v[(l + idx_k) mod 1024]  (unchanged)
// ---------------------------------------------------------------------------
__global__ __launch_bounds__(256) void agg_kernel(
    const float* __restrict__ vp, const float* __restrict__ wvals,
    const int* __restrict__ widx, float* __restrict__ agg) {
  __shared__ float vs[2048];
  __shared__ float wv[13];
  __shared__ int   wi[13];
  const int pair = blockIdx.x;
  const int t = threadIdx.x;
  const float* __restrict__ vg = vp + (size_t)pair * 1024;
  *(float4*)&vs[4 * t]         = *(const float4*)&vg[(4 * t) & 1023];
  *(float4*)&vs[4 * (t + 256)] = *(const float4*)&vg[(4 * (t + 256)) & 1023];
  if (t < 13) { wv[t] = wvals[pair * 16 + t]; wi[t] = widx[pair * 16 + t]; }
  __syncthreads();

  float r0 = 0.f, r1 = 0.f, r2 = 0.f, r3 = 0.f;
#pragma unroll
  for (int k = 0; k < 13; ++k) {
    const float wk = wv[k];
    const int   ik = wi[k];
    r0 += wk * vs[t        + ik];
    r1 += wk * vs[t + 256  + ik];
    r2 += wk * vs[t + 512  + ik];
    r3 += wk * vs[t + 768  + ik];
  }
  float* __restrict__ ag = agg + (size_t)pair * 1024;
  ag[t] = r0; ag[t + 256] = r1; ag[t + 512] = r2; ag[t + 768] = r3;
}

// ---------------------------------------------------------------------------
// Kernel D: out[b][l][h*64+d] = agg[b*64+d][l]  (unchanged)
// ---------------------------------------------------------------------------
__global__ __launch_bounds__(256) void out_kernel(
    const float* __restrict__ agg, float* __restrict__ out) {
  __shared__ float tile[64][65];
  const int blk = blockIdx.x;
  const int b = blk >> 4, lt = blk & 15;
  const int l0 = lt * 64;
  const int t = threadIdx.x;
  const int j = t & 63, qq = t >> 6;

#pragma unroll
  for (int p = 0; p < 16; ++p) {
    const int d = p * 4 + qq;
    tile[d][j] = agg[(size_t)(b * 64 + d) * 1024 + l0 + j];
  }
  __syncthreads();
#pragma unroll
  for (int p = 0; p < 16; ++p) {
    const int jj = p * 4 + qq;
    const float val = tile[j][jj];
    const size_t rowbase = ((size_t)(b * 1024 + l0 + jj)) * 512;
#pragma unroll
    for (int h = 0; h < 8; ++h)
      out[rowbase + h * 64 + j] = val;
  }
}

// ---------------------------------------------------------------------------
extern "C" void kernel_launch(void* const* d_in, const int* in_sizes, int n_in,
                              void* d_out, int out_size, void* d_ws, size_t ws_size,
                              hipStream_t stream) {
  const float* Q  = (const float*)d_in[0];
  const float* K  = (const float*)d_in[1];
  const float* V  = (const float*)d_in[2];
  const float* Wq = (const float*)d_in[3];
  const float* bq = (const float*)d_in[4];
  float* out = (float*)d_out;
  float* ws  = (float*)d_ws;

  float* proj  = ws;                              // 3 * 1048576 floats
  float* agg   = ws + (size_t)3 * PROJ_N;         // 1048576 floats
  float* wvals = ws + (size_t)4 * PROJ_N;         // 1024*16 floats
  int*   widx  = (int*)(ws + (size_t)4 * PROJ_N + 16384);  // 1024*16 ints

  proj_kernel<<<768, 256, 0, stream>>>(Q, K, V, Wq, bq, proj);
  corr_mfma_kernel<<<1024, 256, 0, stream>>>(proj, proj + PROJ_N, wvals, widx);
  agg_kernel<<<1024, 256, 0, stream>>>(proj + (size_t)2 * PROJ_N, wvals, widx, agg);
  out_kernel<<<256, 256, 0, stream>>>(agg, out);
}

// Round 5
// 186.917 us; speedup vs baseline: 1.1782x; 1.0096x over previous
//
#include <hip/hip_runtime.h>
#include <float.h>
#include <math.h>

// Problem constants: B=16, L=1024, D=512, DH=64, H=8, ktop=13
#define PROJ_N (16*64*1024)   // 1048576 floats per projected tensor (layout [b*64+d][l])

using short8_t  = __attribute__((ext_vector_type(8)))  short;
using uint4_t   = __attribute__((ext_vector_type(4)))  unsigned;
using floatx16  = __attribute__((ext_vector_type(16))) float;

// ---------------------------------------------------------------------------
// bf16 helpers: RNE round, pack, and hi/lo split (x = hi + lo)
// ---------------------------------------------------------------------------
__device__ __forceinline__ unsigned bf16r(float x) {
  unsigned u = __float_as_uint(x);
  return (u + 0x7FFFu + ((u >> 16) & 1u)) >> 16;
}
__device__ __forceinline__ unsigned pk_bf16(float x, float y) {
  return bf16r(x) | (bf16r(y) << 16);
}
// split 8 floats into hi/lo bf16 short8 fragments
__device__ __forceinline__ void split8(float4 a, float4 b, short8_t& h, short8_t& l) {
  float f[8] = {a.x, a.y, a.z, a.w, b.x, b.y, b.z, b.w};
  unsigned hp[4], lp[4];
#pragma unroll
  for (int j = 0; j < 4; ++j) {
    unsigned h0 = bf16r(f[2*j]), h1 = bf16r(f[2*j+1]);
    hp[j] = h0 | (h1 << 16);
    float l0 = f[2*j]   - __uint_as_float(h0 << 16);
    float l1 = f[2*j+1] - __uint_as_float(h1 << 16);
    lp[j] = pk_bf16(l0, l1);
  }
  uint4_t hv = {hp[0], hp[1], hp[2], hp[3]};
  uint4_t lv = {lp[0], lp[1], lp[2], lp[3]};
  h = __builtin_bit_cast(short8_t, hv);
  l = __builtin_bit_cast(short8_t, lv);
}

// ---------------------------------------------------------------------------
// Kernel W: Wt_h/Wt_l[d][k] = hi/lo bf16 split of Wq[k][d]  (64 x 512, 128 KB)
// Tiny prelude; result is L2-resident and reused by every proj block.
// ---------------------------------------------------------------------------
__global__ __launch_bounds__(256) void wtrans_kernel(
    const float* __restrict__ Wq, unsigned short* __restrict__ Wth,
    unsigned short* __restrict__ Wtl) {
  const int tg = blockIdx.x * 256 + threadIdx.x;   // 0..32767
  const int d = tg & 63, k = tg >> 6;
  const float x = Wq[k * 64 + d];
  const unsigned h = bf16r(x);
  const float lo = x - __uint_as_float(h << 16);
  Wth[d * 512 + k] = (unsigned short)h;
  Wtl[d * 512 + k] = (unsigned short)bf16r(lo);
}

// ---------------------------------------------------------------------------
// Kernel A (NEW): proj = X @ Wq + bq via split-precision bf16 MFMA, LDS-free.
//   A-operand = Wt[d][k] (hi/lo, direct 16B global loads, L2-resident)
//   B-operand = X[row][k] (natural layout = fragment layout; 2x16B loads + split)
//   C: col=lane&31 -> l (coalesced stores into transposed proj[d][l] layout)
// grid = 768 (3 inputs x 256 tiles of 64 l), block = 128 (2 waves x 32 l).
// Each wave: 32 l x 64 d, full K=512 (32 ksteps x 6 MFMA).
// ---------------------------------------------------------------------------
__global__ __launch_bounds__(128) void proj_kernel(
    const float* __restrict__ Q, const float* __restrict__ K,
    const float* __restrict__ V, const unsigned short* __restrict__ Wth,
    const unsigned short* __restrict__ Wtl, const float* __restrict__ bq,
    float* __restrict__ proj) {
  const int blk  = blockIdx.x;
  const int in   = blk >> 8;            // 0..2
  const int row0 = (blk & 255) << 6;    // global row (b*1024 + l), 64-row tile
  const float* __restrict__ X = (in == 0) ? Q : (in == 1 ? K : V);

  const int tid  = threadIdx.x;
  const int w    = tid >> 6;
  const int lane = tid & 63;
  const int col  = lane & 31;   // l within wave tile / d-row for A
  const int hk   = lane >> 5;

  const int lrow = row0 + w * 32 + col;
  const float* __restrict__ xrow = X + (size_t)lrow * 512;
  const unsigned short* __restrict__ wh0 = Wth + (size_t)col * 512;
  const unsigned short* __restrict__ wl0 = Wtl + (size_t)col * 512;
  const unsigned short* __restrict__ wh1 = wh0 + 32 * 512;
  const unsigned short* __restrict__ wl1 = wl0 + 32 * 512;

  floatx16 acc0 = {0.f,0.f,0.f,0.f,0.f,0.f,0.f,0.f,
                   0.f,0.f,0.f,0.f,0.f,0.f,0.f,0.f};
  floatx16 acc1 = {0.f,0.f,0.f,0.f,0.f,0.f,0.f,0.f,
                   0.f,0.f,0.f,0.f,0.f,0.f,0.f,0.f};

#pragma unroll 2
  for (int ks = 0; ks < 32; ++ks) {
    const int k0 = ks * 16 + hk * 8;
    float4 xa = *(const float4*)&xrow[k0];
    float4 xb = *(const float4*)&xrow[k0 + 4];
    short8_t a0h = *(const short8_t*)&wh0[k0];
    short8_t a0l = *(const short8_t*)&wl0[k0];
    short8_t a1h = *(const short8_t*)&wh1[k0];
    short8_t a1l = *(const short8_t*)&wl1[k0];
    short8_t bh, bl;
    split8(xa, xb, bh, bl);
    acc0 = __builtin_amdgcn_mfma_f32_32x32x16_bf16(a0h, bh, acc0, 0, 0, 0);
    acc1 = __builtin_amdgcn_mfma_f32_32x32x16_bf16(a1h, bh, acc1, 0, 0, 0);
    acc0 = __builtin_amdgcn_mfma_f32_32x32x16_bf16(a0h, bl, acc0, 0, 0, 0);
    acc1 = __builtin_amdgcn_mfma_f32_32x32x16_bf16(a1h, bl, acc1, 0, 0, 0);
    acc0 = __builtin_amdgcn_mfma_f32_32x32x16_bf16(a0l, bh, acc0, 0, 0, 0);
    acc1 = __builtin_amdgcn_mfma_f32_32x32x16_bf16(a1l, bh, acc1, 0, 0, 0);
  }

  // epilogue: bias + coalesced stores. C/D: col(lane&31)=l, m=(r&3)+8*(r>>2)+4*hk
  const int b    = lrow >> 10;
  const int lloc = lrow & 1023;
  float* __restrict__ p = proj + (size_t)in * PROJ_N + ((size_t)(b * 64) << 10) + lloc;
#pragma unroll
  for (int r = 0; r < 16; ++r) {
    const int m = (r & 3) + ((r >> 2) << 3) + (hk << 2);
    p[(size_t)m << 10]        = acc0[r] + bq[m];
    p[(size_t)(m + 32) << 10] = acc1[r] + bq[m + 32];
  }
}

// ---------------------------------------------------------------------------
// Kernel B: circular correlation via SPLIT-PRECISION bf16 MFMA + top-13 +
// softmax + FUSED v-aggregation. One block per (b,d) pair; 4 waves split K.
//   corr[col + 32*row] = sum_kk k_ext[1024+kk-32row] * q_ext[kk+col]
// Then agg[l] = sum_k w_k * v[(l+idx_k) mod 1024]  (v staged in reused LDS).
// ---------------------------------------------------------------------------
__global__ __launch_bounds__(256) void corr_mfma_kernel(
    const float* __restrict__ qp, const float* __restrict__ kp,
    const float* __restrict__ vp, float* __restrict__ agg) {
  __shared__ __align__(16) short qh[2048];   // q_ext hi, linear lines
  __shared__ __align__(16) short ql[2048];   // q_ext lo, linear lines
  __shared__ __align__(16) short kh[2048];   // k_ext hi, line c at phys c^((c>>3)&7)
  __shared__ __align__(16) short kl[2048];   // k_ext lo, swizzled
  __shared__ float corr4[4][1024];           // partials; later reused as vs[2048]
  __shared__ float tv[13];
  __shared__ float sw[13];
  __shared__ int   ts[13];
  __shared__ float rv[4];
  __shared__ int   rs[4];
  __shared__ int   bsh;

  const int pair = blockIdx.x;
  const int tid  = threadIdx.x;
  const int w    = tid >> 6;
  const int lane = tid & 63;
  const int row  = lane & 31;
  const int hk   = lane >> 5;

  const float* __restrict__ qg = qp + (size_t)pair * 1024;
  const float* __restrict__ kg = kp + (size_t)pair * 1024;
  const float* __restrict__ vg = vp + (size_t)pair * 1024;

  // ---- stage q_ext and k_ext as hi/lo bf16 pairs ----
  {
    const int j = (tid << 3) & 1023;          // both exts are periodic copies
    float4 a0 = *(const float4*)&qg[j];
    float4 a1 = *(const float4*)&qg[j + 4];
    short8_t h8, l8;
    split8(a0, a1, h8, l8);
    *(short8_t*)&qh[tid << 3] = h8;
    *(short8_t*)&ql[tid << 3] = l8;
    float4 b0 = *(const float4*)&kg[j];
    float4 b1 = *(const float4*)&kg[j + 4];
    split8(b0, b1, h8, l8);
    const int p = tid ^ ((tid >> 3) & 7);
    *(short8_t*)&kh[p << 3] = h8;
    *(short8_t*)&kl[p << 3] = l8;
  }
  __syncthreads();

  // ---- MFMA over this wave's K-chunk (3 products per step) ----
  floatx16 acc = {0.f,0.f,0.f,0.f,0.f,0.f,0.f,0.f,
                  0.f,0.f,0.f,0.f,0.f,0.f,0.f,0.f};
  const unsigned* __restrict__ qhd = (const unsigned*)qh;
  const unsigned* __restrict__ qld = (const unsigned*)ql;
#pragma unroll
  for (int i = 0; i < 16; ++i) {
    const int k0 = (w << 8) + (i << 4);
    // A fragments: k_ext[1024 + k0 + 8*hk - 32*row .. +7]
    const int e0 = 1024 + k0 + (hk << 3) - (row << 5);
    const int c  = e0 >> 3;
    const int p  = c ^ ((c >> 3) & 7);
    short8_t ah = *(const short8_t*)&kh[p << 3];
    short8_t al = *(const short8_t*)&kl[p << 3];
    // B fragments: q_ext[k0 + 8*hk + row .. +7]  (element-misaligned)
    const int s0 = k0 + (hk << 3) + row;
    const int d0 = s0 >> 1;
    const unsigned sh = (s0 & 1) << 4;
    unsigned w0 = qhd[d0 + 0], w1 = qhd[d0 + 1], w2 = qhd[d0 + 2],
             w3 = qhd[d0 + 3], w4 = qhd[d0 + 4];
    uint4_t buh = { __builtin_amdgcn_alignbit(w1, w0, sh),
                    __builtin_amdgcn_alignbit(w2, w1, sh),
                    __builtin_amdgcn_alignbit(w3, w2, sh),
                    __builtin_amdgcn_alignbit(w4, w3, sh) };
    unsigned x0 = qld[d0 + 0], x1 = qld[d0 + 1], x2 = qld[d0 + 2],
             x3 = qld[d0 + 3], x4 = qld[d0 + 4];
    uint4_t bul = { __builtin_amdgcn_alignbit(x1, x0, sh),
                    __builtin_amdgcn_alignbit(x2, x1, sh),
                    __builtin_amdgcn_alignbit(x3, x2, sh),
                    __builtin_amdgcn_alignbit(x4, x3, sh) };
    short8_t bh = __builtin_bit_cast(short8_t, buh);
    short8_t bl = __builtin_bit_cast(short8_t, bul);
    acc = __builtin_amdgcn_mfma_f32_32x32x16_bf16(ah, bh, acc, 0, 0, 0);
    acc = __builtin_amdgcn_mfma_f32_32x32x16_bf16(ah, bl, acc, 0, 0, 0);
    acc = __builtin_amdgcn_mfma_f32_32x32x16_bf16(al, bh, acc, 0, 0, 0);
  }

  // ---- write partials; C/D layout: col=lane&31, row=(r&3)+8*(r>>2)+4*hk ----
#pragma unroll
  for (int r = 0; r < 16; ++r) {
    const int srow = (r & 3) + ((r >> 2) << 3) + (hk << 2);
    corr4[w][(srow << 5) | row] = acc[r];
  }
  __syncthreads();

  // ---- issue v loads early (T14): latency hides under reduce+topk ----
  float4 vl0 = *(const float4*)&vg[(4 * tid) & 1023];
  float4 vl1 = *(const float4*)&vg[(4 * (tid + 256)) & 1023];

  // ---- reduce 4 partials; each thread owns s = {tid, +256, +512, +768} ----
  float v0 = corr4[0][tid]       + corr4[1][tid]       + corr4[2][tid]       + corr4[3][tid];
  float v1 = corr4[0][tid + 256] + corr4[1][tid + 256] + corr4[2][tid + 256] + corr4[3][tid + 256];
  float v2 = corr4[0][tid + 512] + corr4[1][tid + 512] + corr4[2][tid + 512] + corr4[3][tid + 512];
  float v3 = corr4[0][tid + 768] + corr4[1][tid + 768] + corr4[2][tid + 768] + corr4[3][tid + 768];
  __syncthreads();   // all corr4 reads done; safe to reuse as vs

  // ---- stage v (duplicated to 2048) into reused corr4 space ----
  float* vs = &corr4[0][0];
  *(float4*)&vs[4 * tid]         = vl0;
  *(float4*)&vs[4 * (tid + 256)] = vl1;

  // ---- top-13 via iterative block argmax ----
  for (int r = 0; r < 13; ++r) {
    float bv = v0; int bs = tid;
    if (v1 > bv) { bv = v1; bs = tid + 256; }
    if (v2 > bv) { bv = v2; bs = tid + 512; }
    if (v3 > bv) { bv = v3; bs = tid + 768; }
#pragma unroll
    for (int off = 32; off >= 1; off >>= 1) {
      float ov = __shfl_xor(bv, off, 64);
      int   os = __shfl_xor(bs, off, 64);
      if (ov > bv || (ov == bv && os < bs)) { bv = ov; bs = os; }
    }
    if (lane == 0) { rv[w] = bv; rs[w] = bs; }
    __syncthreads();
    if (tid == 0) {
      float cv = rv[0]; int cs = rs[0];
#pragma unroll
      for (int u = 1; u < 4; ++u)
        if (rv[u] > cv || (rv[u] == cv && rs[u] < cs)) { cv = rv[u]; cs = rs[u]; }
      tv[r] = cv; ts[r] = cs; bsh = cs;
    }
    __syncthreads();
    const int bw = bsh;
    if ((bw & 255) == tid) {
      const int slot = bw >> 8;
      if      (slot == 0) v0 = -FLT_MAX;
      else if (slot == 1) v1 = -FLT_MAX;
      else if (slot == 2) v2 = -FLT_MAX;
      else                v3 = -FLT_MAX;
    }
  }

  // ---- softmax over the 13 values (thread 0) ----
  if (tid == 0) {
    const float mx = tv[0];
    float e[13]; float s = 0.f;
#pragma unroll
    for (int k = 0; k < 13; ++k) { e[k] = __expf(tv[k] - mx); s += e[k]; }
    const float inv = 1.f / s;
#pragma unroll
    for (int k = 0; k < 13; ++k) sw[k] = e[k] * inv;
  }
  __syncthreads();

  // ---- fused aggregation: agg[l] = sum_k w_k * v[(l+idx_k) mod 1024] ----
  float r0 = 0.f, r1 = 0.f, r2 = 0.f, r3 = 0.f;
#pragma unroll
  for (int k2 = 0; k2 < 13; ++k2) {
    const float wk = sw[k2];
    const int   ik = ts[k2];
    r0 += wk * vs[tid        + ik];
    r1 += wk * vs[tid + 256  + ik];
    r2 += wk * vs[tid + 512  + ik];
    r3 += wk * vs[tid + 768  + ik];
  }
  float* __restrict__ ag = agg + (size_t)pair * 1024;
  ag[tid] = r0; ag[tid + 256] = r1; ag[tid + 512] = r2; ag[tid + 768] = r3;
}

// ---------------------------------------------------------------------------
// Kernel D: out[b][l][h*64+d] = agg[b*64+d][l]  (transpose + 8x head copy)
// ---------------------------------------------------------------------------
__global__ __launch_bounds__(256) void out_kernel(
    const float* __restrict__ agg, float* __restrict__ out) {
  __shared__ float tile[64][65];
  const int blk = blockIdx.x;
  const int b = blk >> 4, lt = blk & 15;
  const int l0 = lt * 64;
  const int t = threadIdx.x;
  const int j = t & 63, qq = t >> 6;

#pragma unroll
  for (int p = 0; p < 16; ++p) {
    const int d = p * 4 + qq;
    tile[d][j] = agg[(size_t)(b * 64 + d) * 1024 + l0 + j];
  }
  __syncthreads();
#pragma unroll
  for (int p = 0; p < 16; ++p) {
    const int jj = p * 4 + qq;
    const float val = tile[j][jj];
    const size_t rowbase = ((size_t)(b * 1024 + l0 + jj)) * 512;
#pragma unroll
    for (int h = 0; h < 8; ++h)
      out[rowbase + h * 64 + j] = val;
  }
}

// ---------------------------------------------------------------------------
extern "C" void kernel_launch(void* const* d_in, const int* in_sizes, int n_in,
                              void* d_out, int out_size, void* d_ws, size_t ws_size,
                              hipStream_t stream) {
  const float* Q  = (const float*)d_in[0];
  const float* K  = (const float*)d_in[1];
  const float* V  = (const float*)d_in[2];
  const float* Wq = (const float*)d_in[3];
  const float* bq = (const float*)d_in[4];
  float* out = (float*)d_out;
  float* ws  = (float*)d_ws;

  float* proj = ws;                               // 3 * 1048576 floats
  float* agg  = ws + (size_t)3 * PROJ_N;          // 1048576 floats
  // Wt_h/Wt_l (128 KB) live at agg's base: read only by proj_kernel, then
  // overwritten by corr's agg stores (kernels are stream-serialized).
  unsigned short* Wth = (unsigned short*)agg;     // 64*512 shorts
  unsigned short* Wtl = Wth + 64 * 512;

  wtrans_kernel<<<128, 256, 0, stream>>>(Wq, Wth, Wtl);
  proj_kernel<<<768, 128, 0, stream>>>(Q, K, V, Wth, Wtl, bq, proj);
  corr_mfma_kernel<<<1024, 256, 0, stream>>>(proj, proj + PROJ_N,
                                             proj + (size_t)2 * PROJ_N, agg);
  out_kernel<<<256, 256, 0, stream>>>(agg, out);
}